// Round 22
// baseline (170.590 us; speedup 1.0000x reference)
//
#include <hip/hip_runtime.h>

typedef __bf16 bf16;
typedef __bf16 bf16x8 __attribute__((ext_vector_type(8)));
typedef __bf16 bf16x4 __attribute__((ext_vector_type(4)));
typedef float f32x4 __attribute__((ext_vector_type(4)));
typedef unsigned int uint;

// Problem constants
#define BB 4
#define TT 2048
#define CC 1024
#define HH 16
#define DD 64
#define MM (BB*TT)   // 8192

// softmax scale folded into q: 1/sqrt(64) * log2(e)  (we use exp2 in the kernel)
#define QSCALE (0.125f * 1.4426950408889634f)

#define MFMA_(a,b,c) __builtin_amdgcn_mfma_f32_16x16x32_bf16(a,b,c,0,0,0)

__device__ __forceinline__ void async_copy16(const bf16* g, bf16* l) {
    __builtin_amdgcn_global_load_lds((const __attribute__((address_space(1))) void*)g,
                                     (__attribute__((address_space(3))) void*)l, 16, 0, 0);
}

// single-instruction 2^x (libm exp2f without -ffast-math expands to ~12 insts)
__device__ __forceinline__ float ex2(float x) {
#if __has_builtin(__builtin_amdgcn_exp2f)
    return __builtin_amdgcn_exp2f(x);
#else
    float r; asm("v_exp_f32 %0, %1" : "=v"(r) : "v"(x)); return r;
#endif
}

// cross-l4 sum via permlane swaps (VALU/DPP, no ds pipe).
// CRITICAL: second operand must be an OPAQUE COPY (asm v_mov) — `uint b = a;`
// merges SSA values -> self-swap (round-10 failure root cause).
__device__ __forceinline__ float pl_sum(float x) {
    uint a = __builtin_bit_cast(uint, x), b;
    asm("v_mov_b32 %0, %1" : "=v"(b) : "v"(a));
    asm("v_permlane16_swap_b32 %0, %1" : "+v"(a), "+v"(b));
    float y = __builtin_bit_cast(float, a) + __builtin_bit_cast(float, b);
    uint c = __builtin_bit_cast(uint, y), d;
    asm("v_mov_b32 %0, %1" : "=v"(d) : "v"(c));
    asm("v_permlane32_swap_b32 %0, %1" : "+v"(c), "+v"(d));
    return __builtin_bit_cast(float, c) + __builtin_bit_cast(float, d);
}

// ---------------- merged preprocessing: conv + both weight transposes ----------------
__global__ __launch_bounds__(256) void preproc(
    const float* __restrict__ x, bf16* __restrict__ xb,
    const float* __restrict__ wa, bf16* __restrict__ waT,
    const float* __restrict__ wp, bf16* __restrict__ wpT)
{
    __shared__ bf16 tile[64][65];
    int bid = blockIdx.x;
    if (bid < 2048) {
        int i = (bid * 256 + threadIdx.x) * 4;
        const int stride = 2048 * 256 * 4;
        for (; i < MM * CC; i += stride) {
            float4 v = *(const float4*)(x + i);
            bf16x4 o;
            o[0] = (bf16)v.x; o[1] = (bf16)v.y; o[2] = (bf16)v.z; o[3] = (bf16)v.w;
            *(bf16x4*)(xb + i) = o;
        }
        return;
    }
    const float* in; bf16* out; int K, N, bx, by;
    if (bid < 2816) {
        int id = bid - 2048; in = wa; out = waT; K = CC; N = 3 * CC;
        bx = id % 48; by = id / 48;
    } else {
        int id = bid - 2816; in = wp; out = wpT; K = CC; N = CC;
        bx = id % 16; by = id / 16;
    }
    int n0 = bx * 64, k0 = by * 64;
    int tc = threadIdx.x & 63, tr = threadIdx.x >> 6;
    #pragma unroll
    for (int p = 0; p < 16; ++p) {
        int k = tr + p * 4;
        tile[k][tc] = (bf16)in[(size_t)(k0 + k) * N + n0 + tc];
    }
    __syncthreads();
    #pragma unroll
    for (int p = 0; p < 16; ++p) {
        int n = tr + p * 4;
        out[(size_t)(n0 + n) * K + k0 + tc] = tile[tc][n];
    }
}

// ---------------- GEMM: C[M][N] = A[M][K] @ Bt[N][K]^T + bias ----------------
// 256 threads, BM=BN=128 BK=64, dbuf LDS (64 KB -> 2 blocks/CU).
// READS-FIRST + SPLIT-READ schedule (r13/r15-validated best: 64.6 us, 795 TF).
// MODE 0: q (xQSCALE) and v written d-major [B*H][D][T] with bf16x4 stores;
// k stays [B*H][T][D] (layout locked by attention's LDS A-fragment reads).
template<int MODE>
__global__ __launch_bounds__(256, 2) void gemm8(
    const bf16* __restrict__ A, const bf16* __restrict__ Bt,
    const float* __restrict__ bias,
    void* __restrict__ out0, void* __restrict__ out1, void* __restrict__ out2,
    int M, int N, int K)
{
    constexpr int BM = 128, BN = 128, BK = 64;
    __shared__ bf16 As[2][BM * BK];   // 2 x 16 KB
    __shared__ bf16 Bs[2][BN * BK];   // 2 x 16 KB

    const int bx = blockIdx.x, by = blockIdx.y;
    const int tid = threadIdx.x;
    const int lane = tid & 63, w = tid >> 6;
    const int l15 = lane & 15, l4 = lane >> 4;
    const int wm = w >> 1, wn = w & 1;   // 2M x 2N waves; per-wave 64x64 C

    const bf16* Ab = A + (size_t)(by * BM) * K;
    const bf16* Bb = Bt + (size_t)(bx * BN) * K;

    const int srow = lane >> 3;
    const int scol = ((lane & 7) ^ srow) * 8;
    const int sx = l15 & 7;

    float bv[4];
    #pragma unroll
    for (int n = 0; n < 4; ++n)
        bv[n] = bias[bx * BN + wn * 64 + n * 16 + l15];

    f32x4 acc[4][4] = {};

#define STAGE(PAR, T)                                                              \
    {                                                                              \
        int k0 = (T) * BK;                                                         \
        _Pragma("unroll")                                                          \
        for (int i = 0; i < 4; ++i) {                                              \
            int rbase = i * 32 + w * 8;                                            \
            async_copy16(Ab + (size_t)(rbase + srow) * K + k0 + scol,              \
                         &As[PAR][rbase * BK]);                                    \
        }                                                                          \
        _Pragma("unroll")                                                          \
        for (int i = 0; i < 4; ++i) {                                              \
            int rbase = i * 32 + w * 8;                                            \
            async_copy16(Bb + (size_t)(rbase + srow) * K + k0 + scol,              \
                         &Bs[PAR][rbase * BK]);                                    \
        }                                                                          \
    }

#define READS_K(PAR, KK)                                                           \
    _Pragma("unroll")                                                              \
    for (int n = 0; n < 4; ++n)                                                    \
        bfr[n][KK] = *(const bf16x8*)(&Bs[PAR][(wn * 64 + n * 16 + l15) * 64       \
                                               + (((KK) * 4 + l4) ^ sx) * 8]);     \
    _Pragma("unroll")                                                              \
    for (int m = 0; m < 4; ++m)                                                    \
        afr[m][KK] = *(const bf16x8*)(&As[PAR][(wm * 64 + m * 16 + l15) * 64       \
                                               + (((KK) * 4 + l4) ^ sx) * 8]);

#define MFMA16(KK)                                                                 \
    __builtin_amdgcn_s_setprio(1);                                                 \
    _Pragma("unroll")                                                              \
    for (int m = 0; m < 4; ++m)                                                    \
        _Pragma("unroll")                                                          \
        for (int n = 0; n < 4; ++n)                                                \
            acc[m][n] = MFMA_(afr[m][KK], bfr[n][KK], acc[m][n]);                  \
    __builtin_amdgcn_s_setprio(0);

    // prologue: tiles 0,1 (8 loads each); bias(4) + t0(8) drain via vmcnt(8)
    STAGE(0, 0)
    STAGE(1, 1)
    asm volatile("s_waitcnt vmcnt(8)" ::: "memory");
    __builtin_amdgcn_sched_barrier(0);
    __builtin_amdgcn_s_barrier();
    __builtin_amdgcn_sched_barrier(0);

    // steady state: t = 0..13
    for (int t = 0; t < 14; ++t) {
        int par = t & 1;
        bf16x8 afr[4][2], bfr[4][2];
        READS_K(par, 0)
        asm volatile("s_waitcnt lgkmcnt(0)" ::: "memory");
        __builtin_amdgcn_sched_barrier(0);
        READS_K(par, 1)                     // kk1 reads fly under MFMA16(kk0)
        __builtin_amdgcn_sched_barrier(0);
        MFMA16(0)
        __builtin_amdgcn_sched_barrier(0);
        asm volatile("s_waitcnt lgkmcnt(0)" ::: "memory");   // kk1 landed
        __builtin_amdgcn_sched_barrier(0);
        __builtin_amdgcn_s_barrier();       // WAR gate: all reads of t done
        __builtin_amdgcn_sched_barrier(0);
        STAGE(par, t + 2)                   // overwrite buf[t&1] with t+2
        __builtin_amdgcn_sched_barrier(0);
        MFMA16(1)
        __builtin_amdgcn_sched_barrier(0);
        asm volatile("s_waitcnt vmcnt(8)" ::: "memory");   // t+1 resident (t+2 in flight)
        __builtin_amdgcn_s_barrier();       // publish t+1, under MFMA drain
        __builtin_amdgcn_sched_barrier(0);
    }
    // t = 14: no staging; validate t15 with vmcnt(0)
    {
        bf16x8 afr[4][2], bfr[4][2];
        READS_K(0, 0)
        asm volatile("s_waitcnt lgkmcnt(0)" ::: "memory");
        __builtin_amdgcn_sched_barrier(0);
        READS_K(0, 1)
        __builtin_amdgcn_sched_barrier(0);
        MFMA16(0)
        __builtin_amdgcn_sched_barrier(0);
        asm volatile("s_waitcnt lgkmcnt(0)" ::: "memory");
        __builtin_amdgcn_sched_barrier(0);
        __builtin_amdgcn_s_barrier();
        __builtin_amdgcn_sched_barrier(0);
        MFMA16(1)
        __builtin_amdgcn_sched_barrier(0);
        asm volatile("s_waitcnt vmcnt(0)" ::: "memory");
        __builtin_amdgcn_s_barrier();
        __builtin_amdgcn_sched_barrier(0);
    }
    // t = 15: tail
    {
        bf16x8 afr[4][2], bfr[4][2];
        READS_K(1, 0)
        READS_K(1, 1)
        MFMA16(0)
        MFMA16(1)
    }

#undef STAGE
#undef READS_K
#undef MFMA16

    if constexpr (MODE == 0) {
        int which = bx >> 3;     // 0=q 1=k 2=v (block is uniform; N=3072, BN=128)
        int b = by >> 4;         // by: 16 blocks per batch (BM=128)
        #pragma unroll
        for (int n = 0; n < 4; ++n) {
            int col = bx * 128 + wn * 64 + n * 16 + l15;
            int c = col & 1023;
            int h = c >> 6, d = c & 63;
            size_t bh = (size_t)(b * HH + h);
            #pragma unroll
            for (int m = 0; m < 4; ++m) {
                int row = by * 128 + wm * 64 + m * 16 + l4 * 4;
                int t0 = row & 2047;
                if (which != 1) {
                    // q and v: d-major [bh][d][t], vectorized over t
                    bf16* dst = (bf16*)(which == 0 ? out0 : out2);
                    float sc = (which == 0) ? QSCALE : 1.f;
                    bf16x4 pk;
                    #pragma unroll
                    for (int i = 0; i < 4; ++i) pk[i] = (bf16)((acc[m][n][i] + bv[n]) * sc);
                    *(bf16x4*)(dst + (bh * DD + d) * TT + t0) = pk;
                } else {
                    bf16* dst = (bf16*)out1;
                    #pragma unroll
                    for (int i = 0; i < 4; ++i)
                        dst[(bh * TT + t0 + i) * DD + d] = (bf16)(acc[m][n][i] + bv[n]);
                }
            }
        }
    } else {
        #pragma unroll
        for (int m = 0; m < 4; ++m) {
            #pragma unroll
            for (int n = 0; n < 4; ++n) {
                int row = by * 128 + wm * 64 + m * 16 + l4 * 4;
                int col = bx * 128 + wn * 64 + n * 16 + l15;
                #pragma unroll
                for (int i = 0; i < 4; ++i)
                    ((float*)out0)[(size_t)(row + i) * N + col] = acc[m][n][i] + bv[n];
            }
        }
    }
}

// ---------------- causal flash attention (v8b: dual-q-tile, Q in d-major) ----------------
// r19-validated structure (~59 us). Q now [B*H][D][T] (enables vectorized q-writes
// in gemm<0>); Q-fragment load becomes 16 scalar bf16 loads per thread, ONCE per
// block (amortized over ~25 tiles — negligible; 16-lane t-contiguity = 32B segments).
__global__ __launch_bounds__(512, 4) void attn_kernel(
    const bf16* __restrict__ Qt, const bf16* __restrict__ Kb, const bf16* __restrict__ Vt,
    bf16* __restrict__ Y)
{
    __shared__ bf16 Ks[4][64 * 64];   // 32 KB  [buf][key*64 + d-granules]
    __shared__ bf16 Vs[4][64 * 64];   // 32 KB  [buf][d*64 + key-granules]

    int bh = blockIdx.x;           // 0..63
    int b = bh >> 4, h = bh & 15;

    int tid = threadIdx.x;
    int lane = tid & 63, w = tid >> 6;     // 8 waves
    int l15 = lane & 15, l4 = lane >> 4;
    const int sx = l15 & 7;

    const bf16* Qg = Qt + (size_t)bh * DD * TT;   // [d][t]
    const bf16* Kg = Kb + (size_t)bh * TT * DD;
    const bf16* Vg = Vt + (size_t)bh * DD * TT;

    const int srow = w * 8 + (lane >> 3);
    const int scol = ((lane & 7) ^ (lane >> 3)) * 8;   // pre-swizzled source granule

#define AT_STAGE(BUF, KT)                                                           \
    async_copy16(Kg + (size_t)((KT) * 64 + srow) * DD + scol, &Ks[BUF][w * 512]);   \
    async_copy16(Vg + (size_t)srow * TT + (KT) * 64 + scol, &Vs[BUF][w * 512]);

    int qtA = 15 - (int)blockIdx.y, qtB = (int)blockIdx.y;
    int q0A = qtA * 128 + w * 16, q0B = qtB * 128 + w * 16;
    int NTA = 2 * qtA + 2, NTB = 2 * qtB + 2;   // NTB <= 16 < 18 <= NTA

    bf16x8 qfA[2], qfB[2];
    #pragma unroll
    for (int kk = 0; kk < 2; ++kk) {
        #pragma unroll
        for (int j = 0; j < 8; ++j) {
            size_t drow = (size_t)(kk * 32 + l4 * 8 + j) * TT;
            qfA[kk][j] = Qg[drow + q0A + l15];
            qfB[kk][j] = Qg[drow + q0B + l15];
        }
    }

    f32x4 oA[4] = {}, oB[4] = {};
    float lstA = 0.f, lstB = 0.f;   // per-lane partials; reduced in epilogue

    // softmax + in-reg P butterfly: s -> (pa0, pa1), accumulates lst (no shift)
#define SOFTMAX_P(S, Q0, LST, PA0, PA1)                                             \
    {                                                                               \
        int qr = (Q0) + l15;                                                        \
        if (ktb + 63 > (Q0)) {                                                      \
            _Pragma("unroll")                                                       \
            for (int n = 0; n < 4; ++n) {                                           \
                int keyb = ktb + n * 16 + l4 * 4;                                   \
                _Pragma("unroll")                                                   \
                for (int i = 0; i < 4; ++i)                                         \
                    if (keyb + i > qr) S[n][i] = -1e30f;                            \
            }                                                                       \
        }                                                                           \
        uint pk_[4][2];                                                             \
        float rs = 0.f;                                                             \
        _Pragma("unroll")                                                           \
        for (int n = 0; n < 4; ++n) {                                               \
            float p0 = ex2(S[n][0]);                                                \
            float p1 = ex2(S[n][1]);                                                \
            float p2 = ex2(S[n][2]);                                                \
            float p3 = ex2(S[n][3]);                                                \
            rs += (p0 + p1) + (p2 + p3);                                            \
            asm("v_cvt_pk_bf16_f32 %0, %1, %2" : "=v"(pk_[n][0]) : "v"(p0), "v"(p1));\
            asm("v_cvt_pk_bf16_f32 %0, %1, %2" : "=v"(pk_[n][1]) : "v"(p2), "v"(p3));\
        }                                                                           \
        LST += rs;                                                                  \
        asm("v_permlane32_swap_b32 %0, %1" : "+v"(pk_[0][0]), "+v"(pk_[1][0]));     \
        asm("v_permlane32_swap_b32 %0, %1" : "+v"(pk_[0][1]), "+v"(pk_[1][1]));     \
        asm("v_permlane32_swap_b32 %0, %1" : "+v"(pk_[2][0]), "+v"(pk_[3][0]));     \
        asm("v_permlane32_swap_b32 %0, %1" : "+v"(pk_[2][1]), "+v"(pk_[3][1]));     \
        asm("v_permlane16_swap_b32 %0, %1" : "+v"(pk_[0][0]), "+v"(pk_[1][0]));     \
        asm("v_permlane16_swap_b32 %0, %1" : "+v"(pk_[0][1]), "+v"(pk_[1][1]));     \
        asm("v_permlane16_swap_b32 %0, %1" : "+v"(pk_[2][0]), "+v"(pk_[3][0]));     \
        asm("v_permlane16_swap_b32 %0, %1" : "+v"(pk_[2][1]), "+v"(pk_[3][1]));     \
        uint4 u0 = {pk_[0][0], pk_[0][1], pk_[1][0], pk_[1][1]};                    \
        uint4 u1 = {pk_[2][0], pk_[2][1], pk_[3][0], pk_[3][1]};                    \
        PA0 = __builtin_bit_cast(bf16x8, u0);                                       \
        PA1 = __builtin_bit_cast(bf16x8, u1);                                       \
    }

    // prologue: tiles 0,1 into bufs 0,1
    AT_STAGE(0, 0)
    AT_STAGE(1, 1)
    asm volatile("s_waitcnt vmcnt(2)" ::: "memory");   // tile0 resident (t1 in flight)
    __builtin_amdgcn_s_barrier();

    for (int kt = 0; kt < NTA; ++kt) {
        int buf = kt & 3;
        bool actA = (kt * 64 <= q0A + 15);
        bool actB = (kt < NTB) && (kt * 64 <= q0B + 15);

        if (kt + 2 < NTA) { AT_STAGE((kt + 2) & 3, kt + 2) }

        int ktb = kt * 64;
        bf16x8 paA0, paA1, paB0, paB1;
        bf16x8 vfA[4];
        if (actA | actB) {
            // K fragments read ONCE, feed both QK^Ts
            bf16x8 kf[4][2];
            #pragma unroll
            for (int n = 0; n < 4; ++n)
                #pragma unroll
                for (int kk = 0; kk < 2; ++kk)
                    kf[n][kk] = *(const bf16x8*)(&Ks[buf][(n * 16 + l15) * 64 + ((kk * 4 + l4) ^ sx) * 8]);

            if (actA) {
                f32x4 s[4] = {};
                __builtin_amdgcn_s_setprio(1);
                #pragma unroll
                for (int kk = 0; kk < 2; ++kk)
                    #pragma unroll
                    for (int n = 0; n < 4; ++n)
                        s[n] = MFMA_(kf[n][kk], qfA[kk], s[n]);
                __builtin_amdgcn_s_setprio(0);
                SOFTMAX_P(s, q0A, lstA, paA0, paA1)
            }
            if (actB) {
                f32x4 s[4] = {};
                __builtin_amdgcn_s_setprio(1);
                #pragma unroll
                for (int kk = 0; kk < 2; ++kk)
                    #pragma unroll
                    for (int n = 0; n < 4; ++n)
                        s[n] = MFMA_(kf[n][kk], qfB[kk], s[n]);
                __builtin_amdgcn_s_setprio(0);
                SOFTMAX_P(s, q0B, lstB, paB0, paB1)
            }
            // V kk0 fragments before the barrier (latency hides under barrier wait)
            #pragma unroll
            for (int n = 0; n < 4; ++n)
                vfA[n] = *(const bf16x8*)(&Vs[buf][(n * 16 + l15) * 64 + (l4 ^ sx) * 8]);
        }

        if (kt + 2 < NTA) { asm volatile("s_waitcnt vmcnt(2)" ::: "memory"); }
        else              { asm volatile("s_waitcnt vmcnt(0)" ::: "memory"); }
        __builtin_amdgcn_s_barrier();   // publish tile t+1; PV below overlaps

        if (actA | actB) {
            __builtin_amdgcn_s_setprio(1);
            if (actA) {
                #pragma unroll
                for (int n = 0; n < 4; ++n) oA[n] = MFMA_(paA0, vfA[n], oA[n]);
            }
            if (actB) {
                #pragma unroll
                for (int n = 0; n < 4; ++n) oB[n] = MFMA_(paB0, vfA[n], oB[n]);
            }
            __builtin_amdgcn_s_setprio(0);
            // V kk1 fragments (buf stays valid: overwritten only by tile kt+4)
            bf16x8 vfB[4];
            #pragma unroll
            for (int n = 0; n < 4; ++n)
                vfB[n] = *(const bf16x8*)(&Vs[buf][(n * 16 + l15) * 64 + ((4 + l4) ^ sx) * 8]);
            __builtin_amdgcn_s_setprio(1);
            if (actA) {
                #pragma unroll
                for (int n = 0; n < 4; ++n) oA[n] = MFMA_(paA1, vfB[n], oA[n]);
            }
            if (actB) {
                #pragma unroll
                for (int n = 0; n < 4; ++n) oB[n] = MFMA_(paB1, vfB[n], oB[n]);
            }
            __builtin_amdgcn_s_setprio(0);
        }
    }

    // epilogue: reduce l partials, Y[b][t][h*64+d] = o / l  (both parts)
    {
        float lt = pl_sum(lstA);
        float inv[4];
        #pragma unroll
        for (int i = 0; i < 4; ++i) inv[i] = 1.f / __shfl(lt, l4 * 4 + i);
        #pragma unroll
        for (int i = 0; i < 4; ++i) {
            int t = q0A + l4 * 4 + i;
            #pragma unroll
            for (int n = 0; n < 4; ++n)
                Y[((size_t)(b * TT + t)) * CC + h * DD + n * 16 + l15] = (bf16)(oA[n][i] * inv[i]);
        }
    }
    {
        float lt = pl_sum(lstB);
        float inv[4];
        #pragma unroll
        for (int i = 0; i < 4; ++i) inv[i] = 1.f / __shfl(lt, l4 * 4 + i);
        #pragma unroll
        for (int i = 0; i < 4; ++i) {
            int t = q0B + l4 * 4 + i;
            #pragma unroll
            for (int n = 0; n < 4; ++n)
                Y[((size_t)(b * TT + t)) * CC + h * DD + n * 16 + l15] = (bf16)(oB[n][i] * inv[i]);
        }
    }
#undef AT_STAGE
#undef SOFTMAX_P
}

extern "C" void kernel_launch(void* const* d_in, const int* in_sizes, int n_in,
                              void* d_out, int out_size, void* d_ws, size_t ws_size,
                              hipStream_t stream) {
    const float* x      = (const float*)d_in[0];
    const float* w_attn = (const float*)d_in[1];
    const float* b_attn = (const float*)d_in[2];
    const float* w_proj = (const float*)d_in[3];
    const float* b_proj = (const float*)d_in[4];
    float* out = (float*)d_out;

    bf16* xb  = (bf16*)d_ws;                        // [8192][1024]
    bf16* waT = xb  + (size_t)MM * CC;              // [3072][1024]
    bf16* wpT = waT + (size_t)3 * CC * CC;          // [1024][1024]
    bf16* qt  = wpT + (size_t)CC * CC;              // [B*H][D][T] (d-major, written by gemm8<0>)
    bf16* kb  = qt  + (size_t)MM * CC;              // [B*H][T][D]
    bf16* vt  = kb  + (size_t)MM * CC;              // [B*H][D][T] (written directly by gemm8<0>)
    bf16* yb  = vt  + (size_t)MM * CC;              // [8192][1024] attention output

    preproc<<<3072, 256, 0, stream>>>(x, xb, w_attn, waT, w_proj, wpT);

    gemm8<0><<<dim3(3 * CC / 128, MM / 128), 256, 0, stream>>>(
        xb, waT, b_attn, qt, kb, vt, MM, 3 * CC, CC);

    attn_kernel<<<dim3(BB * HH, 8), 512, 0, stream>>>(qt, kb, vt, yb);

    gemm8<1><<<dim3(CC / 128, MM / 128), 256, 0, stream>>>(
        yb, wpT, b_proj, out, nullptr, nullptr, MM, CC, CC);
}

// Round 23
// 158.229 us; speedup vs baseline: 1.0781x; 1.0781x over previous
//
#include <hip/hip_runtime.h>

typedef __bf16 bf16;
typedef __bf16 bf16x8 __attribute__((ext_vector_type(8)));
typedef __bf16 bf16x4 __attribute__((ext_vector_type(4)));
typedef float f32x4 __attribute__((ext_vector_type(4)));
typedef unsigned int uint;

// Problem constants
#define BB 4
#define TT 2048
#define CC 1024
#define HH 16
#define DD 64
#define MM (BB*TT)   // 8192

// softmax scale folded into q: 1/sqrt(64) * log2(e)  (we use exp2 in the kernel)
#define QSCALE (0.125f * 1.4426950408889634f)

#define MFMA_(a,b,c) __builtin_amdgcn_mfma_f32_16x16x32_bf16(a,b,c,0,0,0)

__device__ __forceinline__ void async_copy16(const bf16* g, bf16* l) {
    __builtin_amdgcn_global_load_lds((const __attribute__((address_space(1))) void*)g,
                                     (__attribute__((address_space(3))) void*)l, 16, 0, 0);
}

// single-instruction 2^x (libm exp2f without -ffast-math expands to ~12 insts)
__device__ __forceinline__ float ex2(float x) {
#if __has_builtin(__builtin_amdgcn_exp2f)
    return __builtin_amdgcn_exp2f(x);
#else
    float r; asm("v_exp_f32 %0, %1" : "=v"(r) : "v"(x)); return r;
#endif
}

// cross-l4 sum via permlane swaps (VALU/DPP, no ds pipe).
// CRITICAL: second operand must be an OPAQUE COPY (asm v_mov) — `uint b = a;`
// merges SSA values -> self-swap (round-10 failure root cause).
__device__ __forceinline__ float pl_sum(float x) {
    uint a = __builtin_bit_cast(uint, x), b;
    asm("v_mov_b32 %0, %1" : "=v"(b) : "v"(a));
    asm("v_permlane16_swap_b32 %0, %1" : "+v"(a), "+v"(b));
    float y = __builtin_bit_cast(float, a) + __builtin_bit_cast(float, b);
    uint c = __builtin_bit_cast(uint, y), d;
    asm("v_mov_b32 %0, %1" : "=v"(d) : "v"(c));
    asm("v_permlane32_swap_b32 %0, %1" : "+v"(c), "+v"(d));
    return __builtin_bit_cast(float, c) + __builtin_bit_cast(float, d);
}

// ---------------- merged preprocessing: conv + both weight transposes ----------------
// blocks [0,2048): x f32 -> xb bf16 (grid-stride)
// blocks [2048,2816): w_attn [1024][3072] -> waT [3072][1024] bf16
// blocks [2816,3072): w_proj [1024][1024] -> wpT [1024][1024] bf16
__global__ __launch_bounds__(256) void preproc(
    const float* __restrict__ x, bf16* __restrict__ xb,
    const float* __restrict__ wa, bf16* __restrict__ waT,
    const float* __restrict__ wp, bf16* __restrict__ wpT)
{
    __shared__ bf16 tile[64][65];
    int bid = blockIdx.x;
    if (bid < 2048) {
        int i = (bid * 256 + threadIdx.x) * 4;
        const int stride = 2048 * 256 * 4;
        for (; i < MM * CC; i += stride) {
            float4 v = *(const float4*)(x + i);
            bf16x4 o;
            o[0] = (bf16)v.x; o[1] = (bf16)v.y; o[2] = (bf16)v.z; o[3] = (bf16)v.w;
            *(bf16x4*)(xb + i) = o;
        }
        return;
    }
    const float* in; bf16* out; int K, N, bx, by;
    if (bid < 2816) {
        int id = bid - 2048; in = wa; out = waT; K = CC; N = 3 * CC;
        bx = id % 48; by = id / 48;
    } else {
        int id = bid - 2816; in = wp; out = wpT; K = CC; N = CC;
        bx = id % 16; by = id / 16;
    }
    int n0 = bx * 64, k0 = by * 64;
    int tc = threadIdx.x & 63, tr = threadIdx.x >> 6;
    #pragma unroll
    for (int p = 0; p < 16; ++p) {
        int k = tr + p * 4;
        tile[k][tc] = (bf16)in[(size_t)(k0 + k) * N + n0 + tc];
    }
    __syncthreads();
    #pragma unroll
    for (int p = 0; p < 16; ++p) {
        int n = tr + p * 4;
        out[(size_t)(n0 + n) * K + k0 + tc] = tile[tc][n];
    }
}

// ---------------- GEMM: C[M][N] = A[M][K] @ Bt[N][K]^T + bias ----------------
// 256 threads, BM=BN=128 BK=64, dbuf LDS (64 KB -> 2 blocks/CU).
// READS-FIRST + SPLIT-READ schedule (r13/r15-validated best: 64.6 us, 795 TF).
template<int MODE>
__global__ __launch_bounds__(256, 2) void gemm8(
    const bf16* __restrict__ A, const bf16* __restrict__ Bt,
    const float* __restrict__ bias,
    void* __restrict__ out0, void* __restrict__ out1, void* __restrict__ out2,
    int M, int N, int K)
{
    constexpr int BM = 128, BN = 128, BK = 64;
    __shared__ bf16 As[2][BM * BK];   // 2 x 16 KB
    __shared__ bf16 Bs[2][BN * BK];   // 2 x 16 KB

    const int bx = blockIdx.x, by = blockIdx.y;
    const int tid = threadIdx.x;
    const int lane = tid & 63, w = tid >> 6;
    const int l15 = lane & 15, l4 = lane >> 4;
    const int wm = w >> 1, wn = w & 1;   // 2M x 2N waves; per-wave 64x64 C

    const bf16* Ab = A + (size_t)(by * BM) * K;
    const bf16* Bb = Bt + (size_t)(bx * BN) * K;

    const int srow = lane >> 3;
    const int scol = ((lane & 7) ^ srow) * 8;
    const int sx = l15 & 7;

    float bv[4];
    #pragma unroll
    for (int n = 0; n < 4; ++n)
        bv[n] = bias[bx * BN + wn * 64 + n * 16 + l15];

    f32x4 acc[4][4] = {};

#define STAGE(PAR, T)                                                              \
    {                                                                              \
        int k0 = (T) * BK;                                                         \
        _Pragma("unroll")                                                          \
        for (int i = 0; i < 4; ++i) {                                              \
            int rbase = i * 32 + w * 8;                                            \
            async_copy16(Ab + (size_t)(rbase + srow) * K + k0 + scol,              \
                         &As[PAR][rbase * BK]);                                    \
        }                                                                          \
        _Pragma("unroll")                                                          \
        for (int i = 0; i < 4; ++i) {                                              \
            int rbase = i * 32 + w * 8;                                            \
            async_copy16(Bb + (size_t)(rbase + srow) * K + k0 + scol,              \
                         &Bs[PAR][rbase * BK]);                                    \
        }                                                                          \
    }

#define READS_K(PAR, KK)                                                           \
    _Pragma("unroll")                                                              \
    for (int n = 0; n < 4; ++n)                                                    \
        bfr[n][KK] = *(const bf16x8*)(&Bs[PAR][(wn * 64 + n * 16 + l15) * 64       \
                                               + (((KK) * 4 + l4) ^ sx) * 8]);     \
    _Pragma("unroll")                                                              \
    for (int m = 0; m < 4; ++m)                                                    \
        afr[m][KK] = *(const bf16x8*)(&As[PAR][(wm * 64 + m * 16 + l15) * 64       \
                                               + (((KK) * 4 + l4) ^ sx) * 8]);

#define MFMA16(KK)                                                                 \
    __builtin_amdgcn_s_setprio(1);                                                 \
    _Pragma("unroll")                                                              \
    for (int m = 0; m < 4; ++m)                                                    \
        _Pragma("unroll")                                                          \
        for (int n = 0; n < 4; ++n)                                                \
            acc[m][n] = MFMA_(afr[m][KK], bfr[n][KK], acc[m][n]);                  \
    __builtin_amdgcn_s_setprio(0);

    // prologue: tiles 0,1 (8 loads each); bias(4) + t0(8) drain via vmcnt(8)
    STAGE(0, 0)
    STAGE(1, 1)
    asm volatile("s_waitcnt vmcnt(8)" ::: "memory");
    __builtin_amdgcn_sched_barrier(0);
    __builtin_amdgcn_s_barrier();
    __builtin_amdgcn_sched_barrier(0);

    // steady state: t = 0..13
    for (int t = 0; t < 14; ++t) {
        int par = t & 1;
        bf16x8 afr[4][2], bfr[4][2];
        READS_K(par, 0)
        asm volatile("s_waitcnt lgkmcnt(0)" ::: "memory");
        __builtin_amdgcn_sched_barrier(0);
        READS_K(par, 1)                     // kk1 reads fly under MFMA16(kk0)
        __builtin_amdgcn_sched_barrier(0);
        MFMA16(0)
        __builtin_amdgcn_sched_barrier(0);
        asm volatile("s_waitcnt lgkmcnt(0)" ::: "memory");   // kk1 landed
        __builtin_amdgcn_sched_barrier(0);
        __builtin_amdgcn_s_barrier();       // WAR gate: all reads of t done
        __builtin_amdgcn_sched_barrier(0);
        STAGE(par, t + 2)                   // overwrite buf[t&1] with t+2
        __builtin_amdgcn_sched_barrier(0);
        MFMA16(1)
        __builtin_amdgcn_sched_barrier(0);
        asm volatile("s_waitcnt vmcnt(8)" ::: "memory");   // t+1 resident (t+2 in flight)
        __builtin_amdgcn_s_barrier();       // publish t+1, under MFMA drain
        __builtin_amdgcn_sched_barrier(0);
    }
    // t = 14: no staging; validate t15 with vmcnt(0)
    {
        bf16x8 afr[4][2], bfr[4][2];
        READS_K(0, 0)
        asm volatile("s_waitcnt lgkmcnt(0)" ::: "memory");
        __builtin_amdgcn_sched_barrier(0);
        READS_K(0, 1)
        __builtin_amdgcn_sched_barrier(0);
        MFMA16(0)
        __builtin_amdgcn_sched_barrier(0);
        asm volatile("s_waitcnt lgkmcnt(0)" ::: "memory");
        __builtin_amdgcn_sched_barrier(0);
        __builtin_amdgcn_s_barrier();
        __builtin_amdgcn_sched_barrier(0);
        MFMA16(1)
        __builtin_amdgcn_sched_barrier(0);
        asm volatile("s_waitcnt vmcnt(0)" ::: "memory");
        __builtin_amdgcn_s_barrier();
        __builtin_amdgcn_sched_barrier(0);
    }
    // t = 15: tail
    {
        bf16x8 afr[4][2], bfr[4][2];
        READS_K(1, 0)
        READS_K(1, 1)
        MFMA16(0)
        MFMA16(1)
    }

#undef STAGE
#undef READS_K
#undef MFMA16

    if constexpr (MODE == 0) {
        int which = bx >> 3;     // 0=q 1=k 2=v (block is uniform; N=3072, BN=128)
        int b = by >> 4;         // by: 16 blocks per batch (BM=128)
        #pragma unroll
        for (int n = 0; n < 4; ++n) {
            int col = bx * 128 + wn * 64 + n * 16 + l15;
            int c = col & 1023;
            int h = c >> 6, d = c & 63;
            size_t bh = (size_t)(b * HH + h);
            #pragma unroll
            for (int m = 0; m < 4; ++m) {
                int row = by * 128 + wm * 64 + m * 16 + l4 * 4;
                int t0 = row & 2047;
                if (which == 2) {
                    bf16x4 pk;
                    #pragma unroll
                    for (int i = 0; i < 4; ++i) pk[i] = (bf16)(acc[m][n][i] + bv[n]);
                    *(bf16x4*)((bf16*)out2 + (bh * DD + d) * TT + t0) = pk;
                } else {
                    bf16* dst = (bf16*)(which == 0 ? out0 : out1);
                    float sc = (which == 0) ? QSCALE : 1.f;
                    #pragma unroll
                    for (int i = 0; i < 4; ++i)
                        dst[(bh * TT + t0 + i) * DD + d] = (bf16)((acc[m][n][i] + bv[n]) * sc);
                }
            }
        }
    } else {
        #pragma unroll
        for (int m = 0; m < 4; ++m) {
            #pragma unroll
            for (int n = 0; n < 4; ++n) {
                int row = by * 128 + wm * 64 + m * 16 + l4 * 4;
                int col = bx * 128 + wn * 64 + n * 16 + l15;
                #pragma unroll
                for (int i = 0; i < 4; ++i)
                    ((float*)out0)[(size_t)(row + i) * N + col] = acc[m][n][i] + bv[n];
            }
        }
    }
}

// ---------------- causal flash attention (v8: dual-q-tile + no-shift softmax) ----------------
// r21-validated best (~59 us). Dual-q-tile fusion preserves cross-block K/V L2
// reuse (512 blocks, 2/CU). Row-major Q ([bh][t][d], 2x b128 fragment loads) —
// the r22 d-major Q variant regressed (32 serial scalar loads at block start).
__global__ __launch_bounds__(512, 4) void attn_kernel(
    const bf16* __restrict__ Q, const bf16* __restrict__ Kb, const bf16* __restrict__ Vt,
    bf16* __restrict__ Y)
{
    __shared__ bf16 Ks[4][64 * 64];   // 32 KB  [buf][key*64 + d-granules]
    __shared__ bf16 Vs[4][64 * 64];   // 32 KB  [buf][d*64 + key-granules]

    int bh = blockIdx.x;           // 0..63
    int b = bh >> 4, h = bh & 15;

    int tid = threadIdx.x;
    int lane = tid & 63, w = tid >> 6;     // 8 waves
    int l15 = lane & 15, l4 = lane >> 4;
    const int sx = l15 & 7;

    const bf16* Qg = Q  + (size_t)bh * TT * DD;
    const bf16* Kg = Kb + (size_t)bh * TT * DD;
    const bf16* Vg = Vt + (size_t)bh * DD * TT;

    const int srow = w * 8 + (lane >> 3);
    const int scol = ((lane & 7) ^ (lane >> 3)) * 8;   // pre-swizzled source granule

#define AT_STAGE(BUF, KT)                                                           \
    async_copy16(Kg + (size_t)((KT) * 64 + srow) * DD + scol, &Ks[BUF][w * 512]);   \
    async_copy16(Vg + (size_t)srow * TT + (KT) * 64 + scol, &Vs[BUF][w * 512]);

    int qtA = 15 - (int)blockIdx.y, qtB = (int)blockIdx.y;
    int q0A = qtA * 128 + w * 16, q0B = qtB * 128 + w * 16;
    int NTA = 2 * qtA + 2, NTB = 2 * qtB + 2;   // NTB <= 16 < 18 <= NTA

    bf16x8 qfA[2], qfB[2];
    #pragma unroll
    for (int kk = 0; kk < 2; ++kk) {
        qfA[kk] = *(const bf16x8*)(Qg + (size_t)(q0A + l15) * DD + kk * 32 + l4 * 8);
        qfB[kk] = *(const bf16x8*)(Qg + (size_t)(q0B + l15) * DD + kk * 32 + l4 * 8);
    }

    f32x4 oA[4] = {}, oB[4] = {};
    float lstA = 0.f, lstB = 0.f;   // per-lane partials; reduced in epilogue

    // softmax + in-reg P butterfly: s -> (pa0, pa1), accumulates lst (no shift)
#define SOFTMAX_P(S, Q0, LST, PA0, PA1)                                             \
    {                                                                               \
        int qr = (Q0) + l15;                                                        \
        if (ktb + 63 > (Q0)) {                                                      \
            _Pragma("unroll")                                                       \
            for (int n = 0; n < 4; ++n) {                                           \
                int keyb = ktb + n * 16 + l4 * 4;                                   \
                _Pragma("unroll")                                                   \
                for (int i = 0; i < 4; ++i)                                         \
                    if (keyb + i > qr) S[n][i] = -1e30f;                            \
            }                                                                       \
        }                                                                           \
        uint pk_[4][2];                                                             \
        float rs = 0.f;                                                             \
        _Pragma("unroll")                                                           \
        for (int n = 0; n < 4; ++n) {                                               \
            float p0 = ex2(S[n][0]);                                                \
            float p1 = ex2(S[n][1]);                                                \
            float p2 = ex2(S[n][2]);                                                \
            float p3 = ex2(S[n][3]);                                                \
            rs += (p0 + p1) + (p2 + p3);                                            \
            asm("v_cvt_pk_bf16_f32 %0, %1, %2" : "=v"(pk_[n][0]) : "v"(p0), "v"(p1));\
            asm("v_cvt_pk_bf16_f32 %0, %1, %2" : "=v"(pk_[n][1]) : "v"(p2), "v"(p3));\
        }                                                                           \
        LST += rs;                                                                  \
        asm("v_permlane32_swap_b32 %0, %1" : "+v"(pk_[0][0]), "+v"(pk_[1][0]));     \
        asm("v_permlane32_swap_b32 %0, %1" : "+v"(pk_[0][1]), "+v"(pk_[1][1]));     \
        asm("v_permlane32_swap_b32 %0, %1" : "+v"(pk_[2][0]), "+v"(pk_[3][0]));     \
        asm("v_permlane32_swap_b32 %0, %1" : "+v"(pk_[2][1]), "+v"(pk_[3][1]));     \
        asm("v_permlane16_swap_b32 %0, %1" : "+v"(pk_[0][0]), "+v"(pk_[1][0]));     \
        asm("v_permlane16_swap_b32 %0, %1" : "+v"(pk_[0][1]), "+v"(pk_[1][1]));     \
        asm("v_permlane16_swap_b32 %0, %1" : "+v"(pk_[2][0]), "+v"(pk_[3][0]));     \
        asm("v_permlane16_swap_b32 %0, %1" : "+v"(pk_[2][1]), "+v"(pk_[3][1]));     \
        uint4 u0 = {pk_[0][0], pk_[0][1], pk_[1][0], pk_[1][1]};                    \
        uint4 u1 = {pk_[2][0], pk_[2][1], pk_[3][0], pk_[3][1]};                    \
        PA0 = __builtin_bit_cast(bf16x8, u0);                                       \
        PA1 = __builtin_bit_cast(bf16x8, u1);                                       \
    }

    // prologue: tiles 0,1 into bufs 0,1
    AT_STAGE(0, 0)
    AT_STAGE(1, 1)
    asm volatile("s_waitcnt vmcnt(2)" ::: "memory");   // tile0 resident (t1 in flight)
    __builtin_amdgcn_s_barrier();

    for (int kt = 0; kt < NTA; ++kt) {
        int buf = kt & 3;
        bool actA = (kt * 64 <= q0A + 15);
        bool actB = (kt < NTB) && (kt * 64 <= q0B + 15);

        if (kt + 2 < NTA) { AT_STAGE((kt + 2) & 3, kt + 2) }

        int ktb = kt * 64;
        bf16x8 paA0, paA1, paB0, paB1;
        bf16x8 vfA[4];
        if (actA | actB) {
            // K fragments read ONCE, feed both QK^Ts
            bf16x8 kf[4][2];
            #pragma unroll
            for (int n = 0; n < 4; ++n)
                #pragma unroll
                for (int kk = 0; kk < 2; ++kk)
                    kf[n][kk] = *(const bf16x8*)(&Ks[buf][(n * 16 + l15) * 64 + ((kk * 4 + l4) ^ sx) * 8]);

            if (actA) {
                f32x4 s[4] = {};
                __builtin_amdgcn_s_setprio(1);
                #pragma unroll
                for (int kk = 0; kk < 2; ++kk)
                    #pragma unroll
                    for (int n = 0; n < 4; ++n)
                        s[n] = MFMA_(kf[n][kk], qfA[kk], s[n]);
                __builtin_amdgcn_s_setprio(0);
                SOFTMAX_P(s, q0A, lstA, paA0, paA1)
            }
            if (actB) {
                f32x4 s[4] = {};
                __builtin_amdgcn_s_setprio(1);
                #pragma unroll
                for (int kk = 0; kk < 2; ++kk)
                    #pragma unroll
                    for (int n = 0; n < 4; ++n)
                        s[n] = MFMA_(kf[n][kk], qfB[kk], s[n]);
                __builtin_amdgcn_s_setprio(0);
                SOFTMAX_P(s, q0B, lstB, paB0, paB1)
            }
            // V kk0 fragments before the barrier (latency hides under barrier wait)
            #pragma unroll
            for (int n = 0; n < 4; ++n)
                vfA[n] = *(const bf16x8*)(&Vs[buf][(n * 16 + l15) * 64 + (l4 ^ sx) * 8]);
        }

        if (kt + 2 < NTA) { asm volatile("s_waitcnt vmcnt(2)" ::: "memory"); }
        else              { asm volatile("s_waitcnt vmcnt(0)" ::: "memory"); }
        __builtin_amdgcn_s_barrier();   // publish tile t+1; PV below overlaps

        if (actA | actB) {
            __builtin_amdgcn_s_setprio(1);
            if (actA) {
                #pragma unroll
                for (int n = 0; n < 4; ++n) oA[n] = MFMA_(paA0, vfA[n], oA[n]);
            }
            if (actB) {
                #pragma unroll
                for (int n = 0; n < 4; ++n) oB[n] = MFMA_(paB0, vfA[n], oB[n]);
            }
            __builtin_amdgcn_s_setprio(0);
            // V kk1 fragments (buf stays valid: overwritten only by tile kt+4)
            bf16x8 vfB[4];
            #pragma unroll
            for (int n = 0; n < 4; ++n)
                vfB[n] = *(const bf16x8*)(&Vs[buf][(n * 16 + l15) * 64 + ((4 + l4) ^ sx) * 8]);
            __builtin_amdgcn_s_setprio(1);
            if (actA) {
                #pragma unroll
                for (int n = 0; n < 4; ++n) oA[n] = MFMA_(paA1, vfB[n], oA[n]);
            }
            if (actB) {
                #pragma unroll
                for (int n = 0; n < 4; ++n) oB[n] = MFMA_(paB1, vfB[n], oB[n]);
            }
            __builtin_amdgcn_s_setprio(0);
        }
    }

    // epilogue: reduce l partials, Y[b][t][h*64+d] = o / l  (both parts)
    {
        float lt = pl_sum(lstA);
        float inv[4];
        #pragma unroll
        for (int i = 0; i < 4; ++i) inv[i] = 1.f / __shfl(lt, l4 * 4 + i);
        #pragma unroll
        for (int i = 0; i < 4; ++i) {
            int t = q0A + l4 * 4 + i;
            #pragma unroll
            for (int n = 0; n < 4; ++n)
                Y[((size_t)(b * TT + t)) * CC + h * DD + n * 16 + l15] = (bf16)(oA[n][i] * inv[i]);
        }
    }
    {
        float lt = pl_sum(lstB);
        float inv[4];
        #pragma unroll
        for (int i = 0; i < 4; ++i) inv[i] = 1.f / __shfl(lt, l4 * 4 + i);
        #pragma unroll
        for (int i = 0; i < 4; ++i) {
            int t = q0B + l4 * 4 + i;
            #pragma unroll
            for (int n = 0; n < 4; ++n)
                Y[((size_t)(b * TT + t)) * CC + h * DD + n * 16 + l15] = (bf16)(oB[n][i] * inv[i]);
        }
    }
#undef AT_STAGE
#undef SOFTMAX_P
}

extern "C" void kernel_launch(void* const* d_in, const int* in_sizes, int n_in,
                              void* d_out, int out_size, void* d_ws, size_t ws_size,
                              hipStream_t stream) {
    const float* x      = (const float*)d_in[0];
    const float* w_attn = (const float*)d_in[1];
    const float* b_attn = (const float*)d_in[2];
    const float* w_proj = (const float*)d_in[3];
    const float* b_proj = (const float*)d_in[4];
    float* out = (float*)d_out;

    bf16* xb  = (bf16*)d_ws;                        // [8192][1024]
    bf16* waT = xb  + (size_t)MM * CC;              // [3072][1024]
    bf16* wpT = waT + (size_t)3 * CC * CC;          // [1024][1024]
    bf16* qb  = wpT + (size_t)CC * CC;              // [B*H][T][D]
    bf16* kb  = qb  + (size_t)MM * CC;              // [B*H][T][D]
    bf16* vt  = kb  + (size_t)MM * CC;              // [B*H][D][T] (written directly by gemm8<0>)
    bf16* yb  = vt  + (size_t)MM * CC;              // [8192][1024] attention output

    preproc<<<3072, 256, 0, stream>>>(x, xb, w_attn, waT, w_proj, wpT);

    gemm8<0><<<dim3(3 * CC / 128, MM / 128), 256, 0, stream>>>(
        xb, waT, b_attn, qb, kb, vt, MM, 3 * CC, CC);

    attn_kernel<<<dim3(BB * HH, 8), 512, 0, stream>>>(qb, kb, vt, yb);

    gemm8<1><<<dim3(CC / 128, MM / 128), 256, 0, stream>>>(
        yb, wpT, b_proj, out, nullptr, nullptr, MM, CC, CC);
}